// Round 1
// baseline (183.181 us; speedup 1.0000x reference)
//
#include <hip/hip_runtime.h>

constexpr int Fdim = 2000;
constexpr int Wdim = 4000;
constexpr int Edim = 16;
constexpr int Hdim = 64;
constexpr int Bdim = 256;
constexpr int FTILE = 4;                       // f-rows per block in main kernel
constexpr float kLog2e = 1.4426950408889634f;

__device__ __forceinline__ float fast_exp2(float x) {
#if __has_builtin(__builtin_amdgcn_exp2f)
  return __builtin_amdgcn_exp2f(x);
#else
  return exp2f(x);
#endif
}
__device__ __forceinline__ float fast_rcp(float x) {
#if __has_builtin(__builtin_amdgcn_rcpf)
  return __builtin_amdgcn_rcpf(x);
#else
  return 1.0f / x;
#endif
}

// --- detect whether mask is 1-byte bool or 4-byte int32 -------------------
// bool layout: random 0/1 bytes everywhere -> bytes at i%4!=0 are ~50% ones.
// int32 layout (values 0/1 little-endian): bytes at i%4!=0 are ALL zero.
__global__ void detect_mask_kernel(const unsigned char* __restrict__ mask,
                                   int* __restrict__ flag) {
  __shared__ int any;
  if (threadIdx.x == 0) any = 0;
  __syncthreads();
  int acc = 0;
  for (int i = threadIdx.x; i < 8192; i += 256)
    if ((i & 3) != 0) acc |= mask[i];
  if (acc) atomicOr(&any, 1);
  __syncthreads();
  if (threadIdx.x == 0) *flag = (any != 0) ? 1 : 0;  // 1 = byte layout
}

// --- prep: fpb2[f][h] = (femb@Ww[:E] + b)*2log2e ;  hpt2[h][w] = (hemb@Ww[E:])*2log2e
// --- plus wusum = sum(Wu)
__global__ __launch_bounds__(256) void prep_kernel(
    const float* __restrict__ femb, const float* __restrict__ hemb,
    const float* __restrict__ Ww, const float* __restrict__ bw,
    const float* __restrict__ Wu,
    float* __restrict__ fpb2, float* __restrict__ hpt2,
    float* __restrict__ wusum) {
  constexpr float S = 2.0f * kLog2e;
  constexpr int NF = Fdim * Hdim;   // 128000
  constexpr int NH = Hdim * Wdim;   // 256000
  int idx = blockIdx.x * 256 + threadIdx.x;
  if (idx < NF) {
    int f = idx >> 6, h = idx & 63;
    float acc = bw[h];
#pragma unroll
    for (int e = 0; e < Edim; ++e)
      acc = fmaf(femb[f * Edim + e], Ww[e * Hdim + h], acc);
    fpb2[idx] = acc * S;
  } else if (idx < NF + NH) {
    int j = idx - NF;
    int h = j / Wdim, w = j - h * Wdim;
    float acc = 0.f;
#pragma unroll
    for (int e = 0; e < Edim; ++e)
      acc = fmaf(hemb[w * Edim + e], Ww[(Edim + e) * Hdim + h], acc);
    hpt2[j] = acc * S;
  } else if (idx < NF + NH + 64) {
    int l = idx - (NF + NH);        // lanes 0..63 of last block's wave 0
    float s = Wu[l];
#pragma unroll
    for (int o = 32; o > 0; o >>= 1) s += __shfl_down(s, o, 64);
    if (l == 0) *wusum = s;
  }
}

// --- main: for each f-tile, one pass over w accumulating
//   den[f]  = sum_w sc(f,w),   cacc[f][e] = sum_w sc(f,w)*hemb[w][e]
// where sc = mask ? exp(wusum - sum_h 2*Wu[h]*rcp(exp(2x)+1)) : 0
__global__ __launch_bounds__(256) void attn_ctx_kernel(
    const float* __restrict__ fpb2, const float* __restrict__ hpt2,
    const float* __restrict__ Wu, const float* __restrict__ wusum_p,
    const unsigned char* mask_b, const int* __restrict__ mflag,
    const float* __restrict__ hemb, float* __restrict__ ctx) {
  const int f0 = blockIdx.x * FTILE;
  const int tid = threadIdx.x;

  __shared__ float4 s_fp[Hdim];          // packed fpb2 for the 4 f's
  __shared__ float s_wu[Hdim];           // 2*Wu[h]
  __shared__ float s_red[4][FTILE][Edim + 1];
  __shared__ float s_tot[FTILE][Edim + 1];

  if (tid < Hdim) {
    s_wu[tid] = 2.0f * Wu[tid];
    float a = fpb2[(f0 + 0) * Hdim + tid];
    float b = fpb2[(f0 + 1) * Hdim + tid];
    float c = fpb2[(f0 + 2) * Hdim + tid];
    float d = fpb2[(f0 + 3) * Hdim + tid];
    s_fp[tid] = make_float4(a, b, c, d);
  }
  __syncthreads();

  const int mbyte = *mflag;
  const float wls = (*wusum_p) * kLog2e;  // wusum * log2e
  const int* mask_i = (const int*)mask_b;

  float den[FTILE];
  float cacc[FTILE][Edim];
#pragma unroll
  for (int fi = 0; fi < FTILE; ++fi) {
    den[fi] = 0.f;
#pragma unroll
    for (int e = 0; e < Edim; ++e) cacc[fi][e] = 0.f;
  }

  for (int w = tid; w < Wdim; w += 256) {
    float sneg[FTILE] = {0.f, 0.f, 0.f, 0.f};
#pragma unroll 4
    for (int h = 0; h < Hdim; ++h) {
      float hp = hpt2[h * Wdim + w];     // coalesced, L2-resident
      float4 fp = s_fp[h];               // LDS broadcast (1 ds_read_b128)
      float wu = s_wu[h];
      sneg[0] = fmaf(wu, fast_rcp(fast_exp2(fp.x + hp) + 1.0f), sneg[0]);
      sneg[1] = fmaf(wu, fast_rcp(fast_exp2(fp.y + hp) + 1.0f), sneg[1]);
      sneg[2] = fmaf(wu, fast_rcp(fast_exp2(fp.z + hp) + 1.0f), sneg[2]);
      sneg[3] = fmaf(wu, fast_rcp(fast_exp2(fp.w + hp) + 1.0f), sneg[3]);
    }
    const float4* hrow = (const float4*)(hemb + (size_t)w * Edim);
    float4 h0 = hrow[0], h1 = hrow[1], h2 = hrow[2], h3 = hrow[3];
    float hr[Edim] = {h0.x, h0.y, h0.z, h0.w, h1.x, h1.y, h1.z, h1.w,
                      h2.x, h2.y, h2.z, h2.w, h3.x, h3.y, h3.z, h3.w};
#pragma unroll
    for (int fi = 0; fi < FTILE; ++fi) {
      const int midx = (f0 + fi) * Wdim + w;
      bool m = mbyte ? (mask_b[midx] != 0) : (mask_i[midx] != 0);
      // score = wusum - sneg ; sc = exp(score)
      float sc = m ? fast_exp2(fmaf(sneg[fi], -kLog2e, wls)) : 0.0f;
      den[fi] += sc;
#pragma unroll
      for (int e = 0; e < Edim; ++e) cacc[fi][e] = fmaf(sc, hr[e], cacc[fi][e]);
    }
  }

  // block reduction: wave shuffle -> LDS -> final
  const int lane = tid & 63, wv = tid >> 6;
#pragma unroll
  for (int fi = 0; fi < FTILE; ++fi) {
    float v = den[fi];
#pragma unroll
    for (int o = 32; o > 0; o >>= 1) v += __shfl_down(v, o, 64);
    if (lane == 0) s_red[wv][fi][0] = v;
#pragma unroll
    for (int e = 0; e < Edim; ++e) {
      float cv = cacc[fi][e];
#pragma unroll
      for (int o = 32; o > 0; o >>= 1) cv += __shfl_down(cv, o, 64);
      if (lane == 0) s_red[wv][fi][1 + e] = cv;
    }
  }
  __syncthreads();
  if (tid < FTILE * (Edim + 1)) {
    int fi = tid / (Edim + 1), k = tid % (Edim + 1);
    s_tot[fi][k] = s_red[0][fi][k] + s_red[1][fi][k] + s_red[2][fi][k] +
                   s_red[3][fi][k];
  }
  __syncthreads();
  if (tid < FTILE * Edim) {
    int fi = tid >> 4, e = tid & 15;
    ctx[(f0 + fi) * Edim + e] = s_tot[fi][1 + e] / s_tot[fi][0];
  }
}

// --- out[b][e] = sum_f values[b][f] * ctx[f][e] ----------------------------
__global__ __launch_bounds__(256) void out_gemv_kernel(
    const float* __restrict__ values, const float* __restrict__ ctx,
    float* __restrict__ out) {
  const int b = blockIdx.x, tid = threadIdx.x;
  float acc[Edim];
#pragma unroll
  for (int e = 0; e < Edim; ++e) acc[e] = 0.f;
  for (int f = tid; f < Fdim; f += 256) {
    float v = values[b * Fdim + f];
    const float4* c4 = (const float4*)(ctx + f * Edim);
    float4 c0 = c4[0], c1 = c4[1], c2 = c4[2], c3 = c4[3];
    float cr[Edim] = {c0.x, c0.y, c0.z, c0.w, c1.x, c1.y, c1.z, c1.w,
                      c2.x, c2.y, c2.z, c2.w, c3.x, c3.y, c3.z, c3.w};
#pragma unroll
    for (int e = 0; e < Edim; ++e) acc[e] = fmaf(v, cr[e], acc[e]);
  }
  __shared__ float s_red[4][Edim];
  const int lane = tid & 63, wv = tid >> 6;
#pragma unroll
  for (int e = 0; e < Edim; ++e) {
    float a = acc[e];
#pragma unroll
    for (int o = 32; o > 0; o >>= 1) a += __shfl_down(a, o, 64);
    if (lane == 0) s_red[wv][e] = a;
  }
  __syncthreads();
  if (tid < Edim)
    out[b * Edim + tid] =
        s_red[0][tid] + s_red[1][tid] + s_red[2][tid] + s_red[3][tid];
}

extern "C" void kernel_launch(void* const* d_in, const int* in_sizes, int n_in,
                              void* d_out, int out_size, void* d_ws,
                              size_t ws_size, hipStream_t stream) {
  const float* values = (const float*)d_in[0];
  const float* femb   = (const float*)d_in[1];
  const float* hemb   = (const float*)d_in[2];
  const float* Ww     = (const float*)d_in[3];
  const float* bw     = (const float*)d_in[4];
  const float* Wu     = (const float*)d_in[5];
  const unsigned char* mask = (const unsigned char*)d_in[6];
  float* out = (float*)d_out;

  // workspace layout (floats): fpb2[F*H] | hpt2[H*W] | ctx[F*E] | wusum | mflag
  float* ws = (float*)d_ws;
  float* fpb2 = ws;                                   // 128000
  float* hpt2 = fpb2 + Fdim * Hdim;                   // 256000
  float* ctx = hpt2 + (size_t)Hdim * Wdim;            // 32000
  float* wusum = ctx + Fdim * Edim;                   // 1
  int* mflag = (int*)(wusum + 1);                     // 1

  detect_mask_kernel<<<dim3(1), dim3(256), 0, stream>>>(mask, mflag);

  constexpr int prep_blocks = (Fdim * Hdim + Hdim * Wdim) / 256 + 1;  // 1501
  prep_kernel<<<dim3(prep_blocks), dim3(256), 0, stream>>>(
      femb, hemb, Ww, bw, Wu, fpb2, hpt2, wusum);

  attn_ctx_kernel<<<dim3(Fdim / FTILE), dim3(256), 0, stream>>>(
      fpb2, hpt2, Wu, wusum, mask, mflag, hemb, ctx);

  out_gemv_kernel<<<dim3(Bdim), dim3(256), 0, stream>>>(values, ctx, out);
}

// Round 2
// 159.713 us; speedup vs baseline: 1.1469x; 1.1469x over previous
//
#include <hip/hip_runtime.h>

constexpr int Fdim = 2000;
constexpr int Wdim = 4000;
constexpr int Edim = 16;
constexpr int Hdim = 64;
constexpr int Bdim = 256;
constexpr int FTILE = 4;      // f-rows per block in main kernel
constexpr int WCHUNKS = 4;    // w-split per f-tile (occupancy!)
constexpr int WCHUNK = Wdim / WCHUNKS;  // 1000
constexpr float kLog2e = 1.4426950408889634f;

__device__ __forceinline__ float fast_exp2(float x) {
#if __has_builtin(__builtin_amdgcn_exp2f)
  return __builtin_amdgcn_exp2f(x);
#else
  return exp2f(x);
#endif
}
__device__ __forceinline__ float fast_rcp(float x) {
#if __has_builtin(__builtin_amdgcn_rcpf)
  return __builtin_amdgcn_rcpf(x);
#else
  return 1.0f / x;
#endif
}

// --- detect whether mask is 1-byte bool or 4-byte int32 -------------------
// bool layout: random 0/1 bytes everywhere -> bytes at i%4!=0 are ~50% ones.
// int32 layout (values 0/1 little-endian): bytes at i%4!=0 are ALL zero.
__global__ void detect_mask_kernel(const unsigned char* __restrict__ mask,
                                   int* __restrict__ flag) {
  __shared__ int any;
  if (threadIdx.x == 0) any = 0;
  __syncthreads();
  int acc = 0;
  for (int i = threadIdx.x; i < 8192; i += 256)
    if ((i & 3) != 0) acc |= mask[i];
  if (acc) atomicOr(&any, 1);
  __syncthreads();
  if (threadIdx.x == 0) *flag = (any != 0) ? 1 : 0;  // 1 = byte layout
}

// --- prep: fpb2[f][h] = (femb@Ww[:E] + b)*2log2e ;  hpt2[h][w] = (hemb@Ww[E:])*2log2e
// --- plus wusum = sum(Wu)
__global__ __launch_bounds__(256) void prep_kernel(
    const float* __restrict__ femb, const float* __restrict__ hemb,
    const float* __restrict__ Ww, const float* __restrict__ bw,
    const float* __restrict__ Wu,
    float* __restrict__ fpb2, float* __restrict__ hpt2,
    float* __restrict__ wusum) {
  constexpr float S = 2.0f * kLog2e;
  constexpr int NF = Fdim * Hdim;   // 128000
  constexpr int NH = Hdim * Wdim;   // 256000
  int idx = blockIdx.x * 256 + threadIdx.x;
  if (idx < NF) {
    int f = idx >> 6, h = idx & 63;
    float acc = bw[h];
#pragma unroll
    for (int e = 0; e < Edim; ++e)
      acc = fmaf(femb[f * Edim + e], Ww[e * Hdim + h], acc);
    fpb2[idx] = acc * S;
  } else if (idx < NF + NH) {
    int j = idx - NF;
    int h = j / Wdim, w = j - h * Wdim;
    float acc = 0.f;
#pragma unroll
    for (int e = 0; e < Edim; ++e)
      acc = fmaf(hemb[w * Edim + e], Ww[(Edim + e) * Hdim + h], acc);
    hpt2[j] = acc * S;
  } else if (idx < NF + NH + 64) {
    int l = idx - (NF + NH);        // lanes 0..63 of last block's wave 0
    float s = Wu[l];
#pragma unroll
    for (int o = 32; o > 0; o >>= 1) s += __shfl_down(s, o, 64);
    if (l == 0) *wusum = s;
  }
}

// --- main: block = (f-tile, w-chunk). One pass over its w-chunk accumulating
//   pden = sum_w sc(f,w),   pcacc[e] = sum_w sc(f,w)*hemb[w][e]
// where sc = mask ? exp(wusum - sum_h 2*Wu[h]*rcp(exp(2x)+1)) : 0
// Partials written to part[(f*WCHUNKS+chunk)*17 + {0 | 1+e}].
__global__ __launch_bounds__(256) void attn_ctx_kernel(
    const float* __restrict__ fpb2, const float* __restrict__ hpt2,
    const float* __restrict__ Wu, const float* __restrict__ wusum_p,
    const unsigned char* mask_b, const int* __restrict__ mflag,
    const float* __restrict__ hemb, float* __restrict__ part) {
  const int f0 = (blockIdx.x >> 2) * FTILE;
  const int chunk = blockIdx.x & (WCHUNKS - 1);
  const int tid = threadIdx.x;

  __shared__ float4 s_fp[Hdim];          // packed fpb2 for the 4 f's
  __shared__ float s_wu[Hdim];           // 2*Wu[h]
  __shared__ float s_red[4][FTILE][Edim + 1];

  if (tid < Hdim) {
    s_wu[tid] = 2.0f * Wu[tid];
    float a = fpb2[(f0 + 0) * Hdim + tid];
    float b = fpb2[(f0 + 1) * Hdim + tid];
    float c = fpb2[(f0 + 2) * Hdim + tid];
    float d = fpb2[(f0 + 3) * Hdim + tid];
    s_fp[tid] = make_float4(a, b, c, d);
  }
  __syncthreads();

  const int mbyte = *mflag;
  const float wls = (*wusum_p) * kLog2e;  // wusum * log2e
  const int* mask_i = (const int*)mask_b;

  float den[FTILE];
  float cacc[FTILE][Edim];
#pragma unroll
  for (int fi = 0; fi < FTILE; ++fi) {
    den[fi] = 0.f;
#pragma unroll
    for (int e = 0; e < Edim; ++e) cacc[fi][e] = 0.f;
  }

  const int wend = (chunk + 1) * WCHUNK;
  for (int w = chunk * WCHUNK + tid; w < wend; w += 256) {
    float sneg[FTILE] = {0.f, 0.f, 0.f, 0.f};
#pragma unroll 4
    for (int h = 0; h < Hdim; ++h) {
      float hp = hpt2[h * Wdim + w];     // coalesced, L2-resident
      float4 fp = s_fp[h];               // LDS broadcast (1 ds_read_b128)
      float wu = s_wu[h];
      sneg[0] = fmaf(wu, fast_rcp(fast_exp2(fp.x + hp) + 1.0f), sneg[0]);
      sneg[1] = fmaf(wu, fast_rcp(fast_exp2(fp.y + hp) + 1.0f), sneg[1]);
      sneg[2] = fmaf(wu, fast_rcp(fast_exp2(fp.z + hp) + 1.0f), sneg[2]);
      sneg[3] = fmaf(wu, fast_rcp(fast_exp2(fp.w + hp) + 1.0f), sneg[3]);
    }
    const float4* hrow = (const float4*)(hemb + (size_t)w * Edim);
    float4 h0 = hrow[0], h1 = hrow[1], h2 = hrow[2], h3 = hrow[3];
    float hr[Edim] = {h0.x, h0.y, h0.z, h0.w, h1.x, h1.y, h1.z, h1.w,
                      h2.x, h2.y, h2.z, h2.w, h3.x, h3.y, h3.z, h3.w};
#pragma unroll
    for (int fi = 0; fi < FTILE; ++fi) {
      const int midx = (f0 + fi) * Wdim + w;
      bool m = mbyte ? (mask_b[midx] != 0) : (mask_i[midx] != 0);
      // score = wusum - sneg ; sc = exp(score)
      float sc = m ? fast_exp2(fmaf(sneg[fi], -kLog2e, wls)) : 0.0f;
      den[fi] += sc;
#pragma unroll
      for (int e = 0; e < Edim; ++e) cacc[fi][e] = fmaf(sc, hr[e], cacc[fi][e]);
    }
  }

  // block reduction: wave shuffle -> LDS -> final partial write
  const int lane = tid & 63, wv = tid >> 6;
#pragma unroll
  for (int fi = 0; fi < FTILE; ++fi) {
    float v = den[fi];
#pragma unroll
    for (int o = 32; o > 0; o >>= 1) v += __shfl_down(v, o, 64);
    if (lane == 0) s_red[wv][fi][0] = v;
#pragma unroll
    for (int e = 0; e < Edim; ++e) {
      float cv = cacc[fi][e];
#pragma unroll
      for (int o = 32; o > 0; o >>= 1) cv += __shfl_down(cv, o, 64);
      if (lane == 0) s_red[wv][fi][1 + e] = cv;
    }
  }
  __syncthreads();
  if (tid < FTILE * (Edim + 1)) {
    int fi = tid / (Edim + 1), k = tid % (Edim + 1);
    float tot = s_red[0][fi][k] + s_red[1][fi][k] + s_red[2][fi][k] +
                s_red[3][fi][k];
    part[((f0 + fi) * WCHUNKS + chunk) * (Edim + 1) + k] = tot;
  }
}

// --- finalize: ctx[f][e] = sum_c num / sum_c den ---------------------------
__global__ __launch_bounds__(256) void finalize_kernel(
    const float* __restrict__ part, float* __restrict__ ctx) {
  int idx = blockIdx.x * 256 + threadIdx.x;
  if (idx >= Fdim * Edim) return;
  int f = idx >> 4, e = idx & 15;
  const float* p = part + f * WCHUNKS * (Edim + 1);
  float den = 0.f, num = 0.f;
#pragma unroll
  for (int c = 0; c < WCHUNKS; ++c) {
    den += p[c * (Edim + 1)];
    num += p[c * (Edim + 1) + 1 + e];
  }
  ctx[idx] = num / den;
}

// --- out[b][e] = sum_f values[b][f] * ctx[f][e] ----------------------------
__global__ __launch_bounds__(256) void out_gemv_kernel(
    const float* __restrict__ values, const float* __restrict__ ctx,
    float* __restrict__ out) {
  const int b = blockIdx.x, tid = threadIdx.x;
  float acc[Edim];
#pragma unroll
  for (int e = 0; e < Edim; ++e) acc[e] = 0.f;
  for (int f = tid; f < Fdim; f += 256) {
    float v = values[b * Fdim + f];
    const float4* c4 = (const float4*)(ctx + f * Edim);
    float4 c0 = c4[0], c1 = c4[1], c2 = c4[2], c3 = c4[3];
    float cr[Edim] = {c0.x, c0.y, c0.z, c0.w, c1.x, c1.y, c1.z, c1.w,
                      c2.x, c2.y, c2.z, c2.w, c3.x, c3.y, c3.z, c3.w};
#pragma unroll
    for (int e = 0; e < Edim; ++e) acc[e] = fmaf(v, cr[e], acc[e]);
  }
  __shared__ float s_red[4][Edim];
  const int lane = tid & 63, wv = tid >> 6;
#pragma unroll
  for (int e = 0; e < Edim; ++e) {
    float a = acc[e];
#pragma unroll
    for (int o = 32; o > 0; o >>= 1) a += __shfl_down(a, o, 64);
    if (lane == 0) s_red[wv][e] = a;
  }
  __syncthreads();
  if (tid < Edim)
    out[b * Edim + tid] =
        s_red[0][tid] + s_red[1][tid] + s_red[2][tid] + s_red[3][tid];
}

extern "C" void kernel_launch(void* const* d_in, const int* in_sizes, int n_in,
                              void* d_out, int out_size, void* d_ws,
                              size_t ws_size, hipStream_t stream) {
  const float* values = (const float*)d_in[0];
  const float* femb   = (const float*)d_in[1];
  const float* hemb   = (const float*)d_in[2];
  const float* Ww     = (const float*)d_in[3];
  const float* bw     = (const float*)d_in[4];
  const float* Wu     = (const float*)d_in[5];
  const unsigned char* mask = (const unsigned char*)d_in[6];
  float* out = (float*)d_out;

  // workspace layout (floats):
  // fpb2[F*H] | hpt2[H*W] | ctx[F*E] | wusum | mflag | part[F*WCHUNKS*17]
  float* ws = (float*)d_ws;
  float* fpb2 = ws;                                   // 128000
  float* hpt2 = fpb2 + Fdim * Hdim;                   // 256000
  float* ctx = hpt2 + (size_t)Hdim * Wdim;            // 32000
  float* wusum = ctx + Fdim * Edim;                   // 1
  int* mflag = (int*)(wusum + 1);                     // 1
  float* part = (float*)(mflag + 1);                  // 2000*4*17 = 136000

  detect_mask_kernel<<<dim3(1), dim3(256), 0, stream>>>(mask, mflag);

  constexpr int prep_blocks = (Fdim * Hdim + Hdim * Wdim) / 256 + 1;  // 1501
  prep_kernel<<<dim3(prep_blocks), dim3(256), 0, stream>>>(
      femb, hemb, Ww, bw, Wu, fpb2, hpt2, wusum);

  attn_ctx_kernel<<<dim3((Fdim / FTILE) * WCHUNKS), dim3(256), 0, stream>>>(
      fpb2, hpt2, Wu, wusum, mask, mflag, hemb, part);

  finalize_kernel<<<dim3((Fdim * Edim + 255) / 256), dim3(256), 0, stream>>>(
      part, ctx);

  out_gemv_kernel<<<dim3(Bdim), dim3(256), 0, stream>>>(values, ctx, out);
}